// Round 1
// baseline (455.809 us; speedup 1.0000x reference)
//
#include <hip/hip_runtime.h>

typedef __attribute__((ext_vector_type(8))) short bf16x8;
typedef __attribute__((ext_vector_type(4))) float f32x4;

#define NTOK 50
#define NP   64
#define CDIM 256
#define NH   8
#define HD   32
#define XP   264   // x/o LDS row pitch (elems): 528B = 132 banks = 4 mod 32
#define QP   40    // q/k pitch: 80B = 20 banks
#define VP   72    // v^T pitch: 144B = 36 banks = 4 mod 32
#define PP   72    // p pitch
#define SCALE 0.17677669529663687f   // 1/sqrt(32)

__device__ __forceinline__ unsigned short f2bf(float f) {
  unsigned int u = __float_as_uint(f);
  unsigned int r = (u + 0x7fffu + ((u >> 16) & 1u)) >> 16;  // RNE
  return (unsigned short)r;
}
__device__ __forceinline__ uint2 pack4(float a0, float a1, float a2, float a3) {
  uint2 r;
  r.x = (unsigned)f2bf(a0) | ((unsigned)f2bf(a1) << 16);
  r.y = (unsigned)f2bf(a2) | ((unsigned)f2bf(a3) << 16);
  return r;
}

// Convert weights to bf16; build masked transposed bias biasT[h][key n][query m].
__global__ void prep_kernel(const float* __restrict__ qkv_w, const float* __restrict__ proj_w,
                            const float* __restrict__ bias_table, const int* __restrict__ rel_idx,
                            unsigned short* __restrict__ wq, unsigned short* __restrict__ wp,
                            float* __restrict__ biasT) {
  int i = blockIdx.x * 256 + threadIdx.x;
  if (i < 768 * 256) wq[i] = f2bf(qkv_w[i]);
  if (i < 256 * 256) wp[i] = f2bf(proj_w[i]);
  if (i < NH * 64 * 64) {
    int h = i >> 12, n = (i >> 6) & 63, m = i & 63;  // n = key, m = query
    float v;
    if (n >= NTOK) v = -1e30f;                        // padded keys: softmax mask
    else if (m == 0 || n == 0 || m >= NTOK) v = 0.f;  // region-token row/col zero-pad
    else v = bias_table[rel_idx[(m - 1) * 49 + (n - 1)] * NH + h];
    biasT[i] = v;
  }
}

__global__ __launch_bounds__(256, 1)
void mhsa_kernel(const float* __restrict__ x, const unsigned short* __restrict__ wqkv,
                 const unsigned short* __restrict__ wproj, const float* __restrict__ biasT,
                 const float* __restrict__ qkv_b, const float* __restrict__ proj_b,
                 float* __restrict__ out) {
  __shared__ unsigned short x_lds[NP * XP];       // 33792 B, aliased as o_lds after QKV
  __shared__ unsigned short q_lds[4][NP * QP];    // per-wave [token][d] bf16
  __shared__ unsigned short k_lds[4][NP * QP];
  __shared__ unsigned short vt_lds[4][HD * VP];   // per-wave V^T [d][token]
  __shared__ unsigned short p_lds[4][NP * PP];    // per-wave P [query][key]

  const int b = blockIdx.x;
  const int tid = (int)threadIdx.x;
  const int w = tid >> 6, lane = tid & 63, g = lane >> 4, m16 = lane & 15;

  // ---- stage x -> bf16 LDS (rows >= 50 zeroed) ----
  {
    const float* xb = x + (size_t)b * NTOK * CDIM;
    int c4 = lane * 4;
    #pragma unroll
    for (int i = 0; i < 16; ++i) {
      int n = i * 4 + w;
      uint2 pv = make_uint2(0u, 0u);
      if (n < NTOK) {
        float4 v = *(const float4*)&xb[n * CDIM + c4];
        pv = pack4(v.x, v.y, v.z, v.w);
      }
      *(uint2*)&x_lds[n * XP + c4] = pv;
    }
  }
  __syncthreads();

  float o_reg[2][4][2][4];  // [pass][mt][dt][r], kept in VGPRs until proj

  #pragma unroll
  for (int pass = 0; pass < 2; ++pass) {
    const int h = w + 4 * pass;  // wave w handles head h this pass

    // ---- Q (scaled, +bias) and K via swapped GEMM: D[j][n] = sum_c W[j,c] x[n,c] ----
    #pragma unroll
    for (int qk = 0; qk < 2; ++qk) {
      const unsigned short* wb = wqkv + ((size_t)(qk * CDIM + h * HD)) * CDIM;
      unsigned short* dst = qk ? k_lds[w] : q_lds[w];
      const float sc = qk ? 1.f : SCALE;
      #pragma unroll
      for (int jt = 0; jt < 2; ++jt) {
        bf16x8 afr[8];
        #pragma unroll
        for (int ks = 0; ks < 8; ++ks)
          afr[ks] = *(const bf16x8*)&wb[(jt * 16 + m16) * CDIM + ks * 32 + g * 8];
        const int jb = qk * CDIM + h * HD + jt * 16 + g * 4;
        const float b0 = qkv_b[jb], b1 = qkv_b[jb + 1], b2 = qkv_b[jb + 2], b3 = qkv_b[jb + 3];
        #pragma unroll
        for (int nt = 0; nt < 4; ++nt) {
          f32x4 acc = {0.f, 0.f, 0.f, 0.f};
          #pragma unroll
          for (int ks = 0; ks < 8; ++ks) {
            bf16x8 bfr = *(const bf16x8*)&x_lds[(nt * 16 + m16) * XP + ks * 32 + g * 8];
            acc = __builtin_amdgcn_mfma_f32_16x16x32_bf16(afr[ks], bfr, acc, 0, 0, 0);
          }
          // 4 regs = 4 consecutive feature idx -> packed b64 into [token][d] layout
          *(uint2*)&dst[(nt * 16 + m16) * QP + jt * 16 + g * 4] =
              pack4((acc[0] + b0) * sc, (acc[1] + b1) * sc, (acc[2] + b2) * sc, (acc[3] + b3) * sc);
        }
      }
    }

    // ---- V normal GEMM: D[n][d] -> store transposed vt[d][n] ----
    {
      const unsigned short* wb = wqkv + ((size_t)(2 * CDIM + h * HD)) * CDIM;
      #pragma unroll
      for (int jt = 0; jt < 2; ++jt) {
        bf16x8 bfrw[8];
        #pragma unroll
        for (int ks = 0; ks < 8; ++ks)
          bfrw[ks] = *(const bf16x8*)&wb[(jt * 16 + m16) * CDIM + ks * 32 + g * 8];
        const float vb = qkv_b[2 * CDIM + h * HD + jt * 16 + m16];
        #pragma unroll
        for (int nt = 0; nt < 4; ++nt) {
          f32x4 acc = {0.f, 0.f, 0.f, 0.f};
          #pragma unroll
          for (int ks = 0; ks < 8; ++ks) {
            bf16x8 afr = *(const bf16x8*)&x_lds[(nt * 16 + m16) * XP + ks * 32 + g * 8];
            acc = __builtin_amdgcn_mfma_f32_16x16x32_bf16(afr, bfrw[ks], acc, 0, 0, 0);
          }
          *(uint2*)&vt_lds[w][(jt * 16 + m16) * VP + nt * 16 + g * 4] =
              pack4(acc[0] + vb, acc[1] + vb, acc[2] + vb, acc[3] + vb);
        }
      }
    }

    // ---- S^T[key n][query m] = K·Q^T (K=32, one MFMA per 16x16 tile) ----
    f32x4 sfr[4][4];
    #pragma unroll
    for (int nt = 0; nt < 4; ++nt) {
      bf16x8 afr = *(const bf16x8*)&k_lds[w][(nt * 16 + m16) * QP + g * 8];
      #pragma unroll
      for (int mtc = 0; mtc < 4; ++mtc) {
        bf16x8 bfr = *(const bf16x8*)&q_lds[w][(mtc * 16 + m16) * QP + g * 8];
        f32x4 z = {0.f, 0.f, 0.f, 0.f};
        sfr[nt][mtc] = __builtin_amdgcn_mfma_f32_16x16x32_bf16(afr, bfr, z, 0, 0, 0);
      }
    }
    // bias (+key mask) add, f32
    const float* bT = biasT + h * 4096;
    #pragma unroll
    for (int nt = 0; nt < 4; ++nt)
      #pragma unroll
      for (int mtc = 0; mtc < 4; ++mtc)
        #pragma unroll
        for (int r = 0; r < 4; ++r)
          sfr[nt][mtc][r] += bT[(nt * 16 + g * 4 + r) * 64 + mtc * 16 + m16];

    // ---- softmax over keys: 16 in-lane values + shfl_xor(16,32) across g-groups ----
    #pragma unroll
    for (int mtc = 0; mtc < 4; ++mtc) {
      float mx = -1e30f;
      #pragma unroll
      for (int nt = 0; nt < 4; ++nt)
        #pragma unroll
        for (int r = 0; r < 4; ++r) mx = fmaxf(mx, sfr[nt][mtc][r]);
      mx = fmaxf(mx, __shfl_xor(mx, 16, 64));
      mx = fmaxf(mx, __shfl_xor(mx, 32, 64));
      float sum = 0.f;
      #pragma unroll
      for (int nt = 0; nt < 4; ++nt)
        #pragma unroll
        for (int r = 0; r < 4; ++r) {
          float e = __expf(sfr[nt][mtc][r] - mx);
          sfr[nt][mtc][r] = e;
          sum += e;
        }
      sum += __shfl_xor(sum, 16, 64);
      sum += __shfl_xor(sum, 32, 64);
      const float inv = 1.f / sum;
      #pragma unroll
      for (int nt = 0; nt < 4; ++nt)
        *(uint2*)&p_lds[w][(mtc * 16 + m16) * PP + nt * 16 + g * 4] =
            pack4(sfr[nt][mtc][0] * inv, sfr[nt][mtc][1] * inv,
                  sfr[nt][mtc][2] * inv, sfr[nt][mtc][3] * inv);
    }

    // ---- O[m][d] = P·V (K=64), keep in registers ----
    #pragma unroll
    for (int mt = 0; mt < 4; ++mt) {
      bf16x8 a0 = *(const bf16x8*)&p_lds[w][(mt * 16 + m16) * PP + 0 * 32 + g * 8];
      bf16x8 a1 = *(const bf16x8*)&p_lds[w][(mt * 16 + m16) * PP + 1 * 32 + g * 8];
      #pragma unroll
      for (int dt = 0; dt < 2; ++dt) {
        bf16x8 b0 = *(const bf16x8*)&vt_lds[w][(dt * 16 + m16) * VP + 0 * 32 + g * 8];
        bf16x8 b1 = *(const bf16x8*)&vt_lds[w][(dt * 16 + m16) * VP + 1 * 32 + g * 8];
        f32x4 acc = {0.f, 0.f, 0.f, 0.f};
        acc = __builtin_amdgcn_mfma_f32_16x16x32_bf16(a0, b0, acc, 0, 0, 0);
        acc = __builtin_amdgcn_mfma_f32_16x16x32_bf16(a1, b1, acc, 0, 0, 0);
        #pragma unroll
        for (int r = 0; r < 4; ++r) o_reg[pass][mt][dt][r] = acc[r];
      }
    }
  }

  __syncthreads();  // all waves done reading x_lds
  // ---- O -> o_lds (aliases x_lds) ----
  unsigned short* o_lds = x_lds;
  #pragma unroll
  for (int pass = 0; pass < 2; ++pass) {
    const int h = w + 4 * pass;
    #pragma unroll
    for (int mt = 0; mt < 4; ++mt)
      #pragma unroll
      for (int dt = 0; dt < 2; ++dt)
        #pragma unroll
        for (int r = 0; r < 4; ++r)
          o_lds[(mt * 16 + g * 4 + r) * XP + h * HD + dt * 16 + m16] =
              f2bf(o_reg[pass][mt][dt][r]);
  }
  __syncthreads();

  // ---- proj: out[n][e] = sum_c O[n,c] Wp[e,c] + pb; wave w owns e in [64w, 64w+64) ----
  const int ebase = w * 64;
  #pragma unroll
  for (int nt = 0; nt < 4; ++nt) {
    bf16x8 afr[8];
    #pragma unroll
    for (int ks = 0; ks < 8; ++ks)
      afr[ks] = *(const bf16x8*)&o_lds[(nt * 16 + m16) * XP + ks * 32 + g * 8];
    #pragma unroll
    for (int et = 0; et < 4; ++et) {
      const int e = ebase + et * 16 + m16;
      f32x4 acc = {0.f, 0.f, 0.f, 0.f};
      #pragma unroll
      for (int ks = 0; ks < 8; ++ks) {
        bf16x8 bfr = *(const bf16x8*)&wproj[(size_t)e * CDIM + ks * 32 + g * 8];
        acc = __builtin_amdgcn_mfma_f32_16x16x32_bf16(afr[ks], bfr, acc, 0, 0, 0);
      }
      const float pb = proj_b[e];
      #pragma unroll
      for (int r = 0; r < 4; ++r) {
        const int n = nt * 16 + g * 4 + r;
        if (n < NTOK) out[((size_t)b * NTOK + n) * CDIM + e] = acc[r] + pb;
      }
    }
  }
}

extern "C" void kernel_launch(void* const* d_in, const int* in_sizes, int n_in,
                              void* d_out, int out_size, void* d_ws, size_t ws_size,
                              hipStream_t stream) {
  const float* x          = (const float*)d_in[0];
  const float* qkv_w      = (const float*)d_in[1];
  const float* qkv_b      = (const float*)d_in[2];
  const float* proj_w     = (const float*)d_in[3];
  const float* proj_b     = (const float*)d_in[4];
  const float* bias_table = (const float*)d_in[5];
  const int*   rel_idx    = (const int*)d_in[6];

  unsigned short* wq = (unsigned short*)d_ws;                  // 768*256 bf16
  unsigned short* wp = wq + 768 * 256;                         // 256*256 bf16
  float* biasT = (float*)(wp + 256 * 256);                     // 8*64*64 f32

  prep_kernel<<<768, 256, 0, stream>>>(qkv_w, proj_w, bias_table, rel_idx, wq, wp, biasT);
  mhsa_kernel<<<2048, 256, 0, stream>>>(x, wq, wp, biasT, qkv_b, proj_b, (float*)d_out);
}